// Round 9
// baseline (112.071 us; speedup 1.0000x reference)
//
#include <hip/hip_runtime.h>
#include <stdint.h>

#define NF     64
#define DIM0   50000
#define SROWS  100000
#define TPB    256
#define NB     196          // buckets of 256 axis0-rows: ceil(50000/256)
#define KSPLIT 8            // workgroups per bucket in query pass
#define QBLKS  3125         // 800000 code-words / 256

// ws layout (bytes)
#define OFF_CODES 0u
#define OFF_COEF  3200000u
#define OFF_CNT   3201536u
#define OFF_BASE  3202560u
#define OFF_CUR   3203584u
#define OFF_REC   3204608u

typedef float    f32x4 __attribute__((ext_vector_type(4)));
typedef uint32_t u32x4 __attribute__((ext_vector_type(4)));
typedef uint32_t u32x2 __attribute__((ext_vector_type(2)));

// ---------------------------------------------------------------------------
// K1 (fused): blocks [0,QBLKS) quantize; blocks [QBLKS,..) histogram idx0.
// Quantize: q = clamp(ceil(16*f - 1), 0, 15) (bit-exact vs jnp.argmin,
// tie->lower; validated r2-r8, absmax <= 2.4e-7). Row = 32B of 4-bit codes.
// Block 0 also derives coefficients W'=W/256, X'=W/512+X/16, Y'=W/512+Y/16,
// C=W/1024+(X+Y)/32+V3 and per-half constant sums Ca,Cb.
// Histogram: per-block LDS counts -> one global atomicAdd per bucket.
// (gcnt zeroed by hipMemsetAsync before this kernel.)
// ---------------------------------------------------------------------------
__global__ __launch_bounds__(TPB) void quanthist_kernel(
        const float* __restrict__ feats, const float* __restrict__ values,
        const int* __restrict__ idx0,
        uint32_t* __restrict__ qcodes, float* __restrict__ coef,
        uint32_t* __restrict__ gcnt, int N) {
    int bid = blockIdx.x;
    int t   = threadIdx.x;

    if (bid < QBLKS) {
        if (bid == 0 && t < NF) {
            float v0 = values[t], v1 = values[NF + t];
            float v2 = values[2 * NF + t], v3 = values[3 * NF + t];
            float W = v0 - v1 - v2 + v3;
            float X = v1 - v3, Y = v2 - v3;
            float Wp = W * (1.0f / 256.0f);
            float Xp = W * (1.0f / 512.0f) + X * (1.0f / 16.0f);
            float Yp = W * (1.0f / 512.0f) + Y * (1.0f / 16.0f);
            float C  = W * (1.0f / 1024.0f) + (X + Y) * (1.0f / 32.0f) + v3;
            ((f32x4*)coef)[t] = (f32x4){Wp, Xp, Yp, C};
            float Cs = C;
            Cs += __shfl_xor(Cs, 1);  Cs += __shfl_xor(Cs, 2);
            Cs += __shfl_xor(Cs, 4);  Cs += __shfl_xor(Cs, 8);
            Cs += __shfl_xor(Cs, 16);
            if (t == 0)  coef[NF * 4 + 0] = Cs;
            if (t == 32) coef[NF * 4 + 1] = Cs;
        }
        int gid = bid * TPB + t;                 // word idx = s*8+w
        const f32x4* fr = (const f32x4*)(feats + (size_t)gid * 8);
        f32x4 fA = __builtin_nontemporal_load(fr);
        f32x4 fB = __builtin_nontemporal_load(fr + 1);
        float fv[8] = {fA.x, fA.y, fA.z, fA.w, fB.x, fB.y, fB.z, fB.w};
        uint32_t word = 0u;
#pragma unroll
        for (int j = 0; j < 8; ++j) {
            float x = fmaf(fv[j], 16.0f, -1.0f); // exact: 16f-1 representable
            int q = (int)ceilf(x);
            q = q < 0 ? 0 : (q > 15 ? 15 : q);
            word |= (uint32_t)q << (4 * j);
        }
        qcodes[gid] = word;
    } else {
        __shared__ uint32_t scnt[NB];
        for (int i = t; i < NB; i += TPB) scnt[i] = 0;
        __syncthreads();
        int q0 = (bid - QBLKS) * 1024;
#pragma unroll
        for (int k = 0; k < 4; ++k) {
            int n = q0 + k * TPB + t;
            if (n < N) atomicAdd(&scnt[(uint32_t)idx0[n] >> 8], 1u);
        }
        __syncthreads();
        for (int i = t; i < NB; i += TPB)
            if (scnt[i]) atomicAdd(&gcnt[i], scnt[i]);
    }
}

// ---------------------------------------------------------------------------
// K2: serial prefix sum over 196 buckets; cursor := base.
// ---------------------------------------------------------------------------
__global__ void prefix_kernel(const uint32_t* __restrict__ cnt,
                              uint32_t* __restrict__ base,
                              uint32_t* __restrict__ cursor) {
    if (threadIdx.x == 0 && blockIdx.x == 0) {
        uint32_t acc = 0;
        for (int i = 0; i < NB; ++i) {
            base[i] = acc; cursor[i] = acc; acc += cnt[i];
        }
        base[NB] = acc;
    }
}

// ---------------------------------------------------------------------------
// K3: scatter queries into bucket-contiguous records.
//   rec = { n | (r0&255)<<20 , r1 }   (N <= 2^20)
// Block-aggregated: LDS count -> one global atomicAdd per (block,bucket)
// claims a range -> LDS rank assigns positions. Intra-bucket order is
// nondeterministic; final output is order-independent.
// ---------------------------------------------------------------------------
__global__ __launch_bounds__(TPB) void scatter_kernel(
        const int* __restrict__ idx0, const int* __restrict__ idx1,
        uint32_t* __restrict__ cursor, uint2* __restrict__ rec, int N) {
    __shared__ uint32_t scnt[NB];
    __shared__ uint32_t sstart[NB];
    int t = threadIdx.x;
    for (int i = t; i < NB; i += TPB) scnt[i] = 0;
    __syncthreads();

    int q0 = blockIdx.x * 1024;
    int r0v[4], r1v[4], bk[4];
#pragma unroll
    for (int k = 0; k < 4; ++k) {
        int n = q0 + k * TPB + t;
        if (n < N) {
            r0v[k] = __builtin_nontemporal_load(idx0 + n);
            r1v[k] = __builtin_nontemporal_load(idx1 + n);
            bk[k] = (uint32_t)r0v[k] >> 8;
            atomicAdd(&scnt[bk[k]], 1u);
        } else bk[k] = -1;
    }
    __syncthreads();
    for (int i = t; i < NB; i += TPB) {
        uint32_t c = scnt[i];
        sstart[i] = c ? atomicAdd(&cursor[i], c) : 0u;
    }
    __syncthreads();
    for (int i = t; i < NB; i += TPB) scnt[i] = 0;
    __syncthreads();
#pragma unroll
    for (int k = 0; k < 4; ++k) {
        if (bk[k] >= 0) {
            int n = q0 + k * TPB + t;
            uint32_t r = atomicAdd(&scnt[bk[k]], 1u);
            uint32_t pos = sstart[bk[k]] + r;
            rec[pos] = make_uint2((uint32_t)n | ((uint32_t)(r0v[k] & 255) << 20),
                                  (uint32_t)r1v[k]);
        }
    }
}

// ---------------------------------------------------------------------------
// K4: binned query. Block (b,k): stage bucket b's 8KB axis0 slice in LDS,
// process its k-th query chunk. r0 row from LDS (free), r1 row from the
// 1.6MB L2-resident axis1 table, out[n] scattered nt-store.
//   per feature (7 ops): acc = fma(A, fma(W',B,X'), fma(Y',B,acc))
// ---------------------------------------------------------------------------
__global__ __launch_bounds__(TPB) void bquery_kernel(
        const uint32_t* __restrict__ qcodes,
        const uint2* __restrict__ rec,
        const uint32_t* __restrict__ base,
        const f32x4* __restrict__ coef,
        const float* __restrict__ scale,
        const float* __restrict__ bias,
        float* __restrict__ out) {
    __shared__ uint32_t lds[256 * 8];
    int b = blockIdx.x / KSPLIT;
    int k = blockIdx.x % KSPLIT;
    int t = threadIdx.x;

    int row0  = b * 256;
    int nrows = min(256, DIM0 - row0);
    int words = nrows * 8;
    for (int i = t; i < words; i += TPB)
        lds[i] = qcodes[(size_t)row0 * 8 + i];

    uint32_t s = base[b], e = base[b + 1];
    __syncthreads();

    uint32_t len   = e - s;
    uint32_t chunk = (len + KSPLIT - 1) / KSPLIT;
    uint32_t start = s + (uint32_t)k * chunk;
    uint32_t end   = min(start + chunk, e);

    float es = expf(scale[0]);
    float bi = bias[0];
    const float* cs = (const float*)coef;
    float Ca = cs[NF * 4 + 0];
    float Cb = cs[NF * 4 + 1];

    for (uint32_t i = start + t; i < end; i += TPB) {
        u32x2 rc = __builtin_nontemporal_load((const u32x2*)(rec + i));
        uint32_t n    = rc.x & 0xFFFFFu;
        uint32_t r0lo = (rc.x >> 20) & 0xFFu;
        uint32_t r1   = rc.y;

        const uint32_t* ar = &lds[r0lo * 8];
        uint32_t aw[8];
#pragma unroll
        for (int w = 0; w < 8; ++w) aw[w] = ar[w];
        const u32x4* pb = (const u32x4*)(qcodes + ((size_t)DIM0 + r1) * 8);
        u32x4 y0 = pb[0], y1 = pb[1];
        uint32_t bw[8] = {y0.x, y0.y, y0.z, y0.w, y1.x, y1.y, y1.z, y1.w};

        float a1 = 0.f, b1 = 0.f;
#pragma unroll
        for (int wd = 0; wd < 8; ++wd) {
#pragma unroll
            for (int j = 0; j < 8; ++j) {
                int f = wd * 8 + j;
                f32x4 c = coef[f];                   // uniform -> s_load
                float A = (float)((aw[wd] >> (4 * j)) & 15u);
                float B = (float)((bw[wd] >> (4 * j)) & 15u);
                float h = fmaf(c.x, B, c.y);         // W'*B + X'
                float g = fmaf(c.z, B, (wd < 4 ? a1 : b1));
                if (wd < 4) a1 = fmaf(A, h, g);
                else        b1 = fmaf(A, h, g);
            }
        }
        float res = (a1 + Ca) * tanhf(b1 + Cb) * es + bi;
        __builtin_nontemporal_store(res, out + n);
    }
}

extern "C" void kernel_launch(void* const* d_in, const int* in_sizes, int n_in,
                              void* d_out, int out_size, void* d_ws, size_t ws_size,
                              hipStream_t stream) {
    const float* values = (const float*)d_in[0];  // [1,4,64]
    const float* feats  = (const float*)d_in[1];  // [100000,64]
    const float* scale  = (const float*)d_in[3];  // [1]
    const float* bias   = (const float*)d_in[4];  // [1]
    const int*   idx0   = (const int*)d_in[5];    // [N]
    const int*   idx1   = (const int*)d_in[6];    // [N]
    float*       out    = (float*)d_out;          // [N] f32

    char* ws = (char*)d_ws;
    uint32_t* qcodes = (uint32_t*)(ws + OFF_CODES);   // 3.2 MB
    float*    coef   = (float*)   (ws + OFF_COEF);    // 258 floats
    uint32_t* gcnt   = (uint32_t*)(ws + OFF_CNT);     // [NB]
    uint32_t* gbase  = (uint32_t*)(ws + OFF_BASE);    // [NB+1]
    uint32_t* gcur   = (uint32_t*)(ws + OFF_CUR);     // [NB]
    uint2*    rec    = (uint2*)   (ws + OFF_REC);     // [N] 8B

    int N = out_size;
    int hblks = (N + 1023) / 1024;

    hipMemsetAsync(gcnt, 0, NB * sizeof(uint32_t), stream);
    quanthist_kernel<<<QBLKS + hblks, TPB, 0, stream>>>(
        feats, values, idx0, qcodes, coef, gcnt, N);
    prefix_kernel<<<1, 64, 0, stream>>>(gcnt, gbase, gcur);
    scatter_kernel<<<hblks, TPB, 0, stream>>>(idx0, idx1, gcur, rec, N);
    bquery_kernel<<<NB * KSPLIT, TPB, 0, stream>>>(
        qcodes, rec, gbase, (const f32x4*)coef, scale, bias, out);
}

// Round 10
// 65.567 us; speedup vs baseline: 1.7093x; 1.7093x over previous
//
#include <hip/hip_runtime.h>
#include <stdint.h>

#define NF     64
#define DIM0   50000
#define SROWS  100000
#define TPB    256
#define NBKT   8            // buckets = axis0 row ranges of 6250 -> XCD-steered
#define BROWS  6250
#define CAP    160000u      // records per bucket region (mean 125K, +28% slack)
#define NCH    512          // chunks per bucket in query pass
#define QBLKS  3125         // 800000 code-words / 256

// ws layout (bytes, 16-aligned)
#define OFF_CODES 0u
#define OFF_COEF  3200000u  // 258 floats
#define OFF_CUR   3202048u  // 8 u32 cursors
#define OFF_REC   3203072u  // 8 * CAP * 8B = 10.24 MB

typedef float    f32x4 __attribute__((ext_vector_type(4)));
typedef uint32_t u32x4 __attribute__((ext_vector_type(4)));

// ---------------------------------------------------------------------------
// K1: closed-form quantize (row = 32B, 64 x 4-bit codes) + coef table.
//   q = clamp(ceil(16*f - 1), 0, 15)  (bit-exact vs jnp.argmin, tie->lower;
//   validated r2-r9, absmax <= 2.4e-7)
// Block 0 wave 0 derives coefficients W'=W/256, X'=W/512+X/16, Y'=W/512+Y/16,
// C=W/1024+(X+Y)/32+V3 (W=V0-V1-V2+V3, X=V1-V3, Y=V2-V3) + half-sums Ca,Cb.
// ---------------------------------------------------------------------------
__global__ __launch_bounds__(TPB) void quantize_kernel(
        const float* __restrict__ feats, const float* __restrict__ values,
        uint32_t* __restrict__ qcodes, float* __restrict__ coef) {
    int t = threadIdx.x;
    if (blockIdx.x == 0 && t < NF) {
        float v0 = values[t], v1 = values[NF + t];
        float v2 = values[2 * NF + t], v3 = values[3 * NF + t];
        float W = v0 - v1 - v2 + v3;
        float X = v1 - v3, Y = v2 - v3;
        float Wp = W * (1.0f / 256.0f);
        float Xp = W * (1.0f / 512.0f) + X * (1.0f / 16.0f);
        float Yp = W * (1.0f / 512.0f) + Y * (1.0f / 16.0f);
        float C  = W * (1.0f / 1024.0f) + (X + Y) * (1.0f / 32.0f) + v3;
        ((f32x4*)coef)[t] = (f32x4){Wp, Xp, Yp, C};
        float Cs = C;
        Cs += __shfl_xor(Cs, 1);  Cs += __shfl_xor(Cs, 2);
        Cs += __shfl_xor(Cs, 4);  Cs += __shfl_xor(Cs, 8);
        Cs += __shfl_xor(Cs, 16);
        if (t == 0)  coef[NF * 4 + 0] = Cs;
        if (t == 32) coef[NF * 4 + 1] = Cs;
    }

    int gid = blockIdx.x * TPB + t;              // word idx = s*8+w (exact)
    const f32x4* fr = (const f32x4*)(feats + (size_t)gid * 8);
    f32x4 fA = __builtin_nontemporal_load(fr);
    f32x4 fB = __builtin_nontemporal_load(fr + 1);
    float fv[8] = {fA.x, fA.y, fA.z, fA.w, fB.x, fB.y, fB.z, fB.w};

    uint32_t word = 0u;
#pragma unroll
    for (int j = 0; j < 8; ++j) {
        float x = fmaf(fv[j], 16.0f, -1.0f);     // exact: 16f-1 representable
        int q = (int)ceilf(x);
        q = q < 0 ? 0 : (q > 15 ? 15 : q);
        word |= (uint32_t)q << (4 * j);
    }
    qcodes[gid] = word;
}

// ---------------------------------------------------------------------------
// K2: scatter queries into 8 fixed-capacity bucket regions.
//   bucket = r0 / 6250 ; rec = { n, r0<<16 | r1 }  (both indices < 2^16)
// LDS rank + one global atomicAdd per (block,bucket). Intra-bucket order is
// nondeterministic; each out[n] is computed identically -> output determ.
// ---------------------------------------------------------------------------
__global__ __launch_bounds__(TPB) void scatter_kernel(
        const int* __restrict__ idx0, const int* __restrict__ idx1,
        uint32_t* __restrict__ cursor, uint2* __restrict__ rec, int N) {
    __shared__ uint32_t scnt[NBKT], sstart[NBKT];
    int t = threadIdx.x;
    if (t < NBKT) scnt[t] = 0;
    __syncthreads();

    int q0 = blockIdx.x * 1024;
    int r0v[4], r1v[4], bk[4];
    uint32_t rk[4];
#pragma unroll
    for (int k = 0; k < 4; ++k) {
        int n = q0 + k * TPB + t;
        if (n < N) {
            r0v[k] = __builtin_nontemporal_load(idx0 + n);
            r1v[k] = __builtin_nontemporal_load(idx1 + n);
            bk[k]  = (uint32_t)r0v[k] / BROWS;
            rk[k]  = atomicAdd(&scnt[bk[k]], 1u);
        } else bk[k] = -1;
    }
    __syncthreads();
    if (t < NBKT) sstart[t] = scnt[t] ? atomicAdd(&cursor[t], scnt[t]) : 0u;
    __syncthreads();
#pragma unroll
    for (int k = 0; k < 4; ++k) {
        if (bk[k] >= 0) {
            int n = q0 + k * TPB + t;
            uint32_t pos = (uint32_t)bk[k] * CAP + sstart[bk[k]] + rk[k];
            rec[pos] = make_uint2((uint32_t)n,
                                  ((uint32_t)r0v[k] << 16) | (uint32_t)r1v[k]);
        }
    }
}

// ---------------------------------------------------------------------------
// K3: XCD-steered binned query. Block handles bucket b = blockIdx&7, chunk
// blockIdx>>3. With round-robin block->XCD mapping, XCD b's L2 only caches
// axis0 rows [b*6250,(b+1)*6250) (200KB) + axis1 table (1.6MB) -> resident.
//   per feature (7 ops): acc = fma(A, fma(W',B,X'), fma(Y',B,acc))
// out[n]: NORMAL cached store (r9 lesson: nt scattered stores = 73MB HBM).
// ---------------------------------------------------------------------------
__global__ __launch_bounds__(TPB) void bquery_kernel(
        const uint32_t* __restrict__ qcodes,
        const uint2* __restrict__ rec,
        const uint32_t* __restrict__ cursor,
        const f32x4* __restrict__ coef,
        const float* __restrict__ scale,
        const float* __restrict__ bias,
        float* __restrict__ out) {
    int b  = blockIdx.x & (NBKT - 1);
    int ch = blockIdx.x >> 3;

    uint32_t cnt = min(cursor[b], CAP);
    uint32_t per = (cnt + NCH - 1) / NCH;
    uint32_t s   = min(per * (uint32_t)ch, cnt);
    uint32_t e   = min(s + per, cnt);
    uint32_t rbase = (uint32_t)b * CAP;

    const float* cs = (const float*)coef;
    float Ca = cs[NF * 4 + 0];
    float Cb = cs[NF * 4 + 1];
    float es = expf(scale[0]);
    float bi = bias[0];

    for (uint32_t i = s + threadIdx.x; i < e; i += TPB) {
        uint2 rc = rec[rbase + i];
        uint32_t n  = rc.x;
        uint32_t r0 = rc.y >> 16;
        uint32_t r1 = rc.y & 0xFFFFu;

        const u32x4* pa = (const u32x4*)(qcodes + (size_t)r0 * 8);
        const u32x4* pb = (const u32x4*)(qcodes + ((size_t)DIM0 + r1) * 8);
        u32x4 x0 = pa[0], x1 = pa[1];
        u32x4 y0 = pb[0], y1 = pb[1];
        uint32_t aw[8] = {x0.x, x0.y, x0.z, x0.w, x1.x, x1.y, x1.z, x1.w};
        uint32_t bw[8] = {y0.x, y0.y, y0.z, y0.w, y1.x, y1.y, y1.z, y1.w};

        float a1 = 0.f, b1 = 0.f;
#pragma unroll
        for (int wd = 0; wd < 8; ++wd) {
#pragma unroll
            for (int j = 0; j < 8; ++j) {
                int f = wd * 8 + j;
                f32x4 c = coef[f];                   // uniform -> s_load
                float A = (float)((aw[wd] >> (4 * j)) & 15u);
                float B = (float)((bw[wd] >> (4 * j)) & 15u);
                float h = fmaf(c.x, B, c.y);         // W'*B + X'
                float g = fmaf(c.z, B, (wd < 4 ? a1 : b1));
                if (wd < 4) a1 = fmaf(A, h, g);
                else        b1 = fmaf(A, h, g);
            }
        }
        out[n] = (a1 + Ca) * tanhf(b1 + Cb) * es + bi;   // cached store
    }
}

extern "C" void kernel_launch(void* const* d_in, const int* in_sizes, int n_in,
                              void* d_out, int out_size, void* d_ws, size_t ws_size,
                              hipStream_t stream) {
    const float* values = (const float*)d_in[0];  // [1,4,64]
    const float* feats  = (const float*)d_in[1];  // [100000,64]
    const float* scale  = (const float*)d_in[3];  // [1]
    const float* bias   = (const float*)d_in[4];  // [1]
    const int*   idx0   = (const int*)d_in[5];    // [N]
    const int*   idx1   = (const int*)d_in[6];    // [N]
    float*       out    = (float*)d_out;          // [N] f32

    char* ws = (char*)d_ws;
    uint32_t* qcodes = (uint32_t*)(ws + OFF_CODES);   // 3.2 MB
    float*    coef   = (float*)   (ws + OFF_COEF);    // 258 floats
    uint32_t* gcur   = (uint32_t*)(ws + OFF_CUR);     // [8]
    uint2*    rec    = (uint2*)   (ws + OFF_REC);     // 8*CAP*8B = 10.24 MB

    int N = out_size;
    int sblks = (N + 1023) / 1024;

    hipMemsetAsync(gcur, 0, NBKT * sizeof(uint32_t), stream);
    quantize_kernel<<<QBLKS, TPB, 0, stream>>>(feats, values, qcodes, coef);
    scatter_kernel<<<sblks, TPB, 0, stream>>>(idx0, idx1, gcur, rec, N);
    bquery_kernel<<<NBKT * NCH, TPB, 0, stream>>>(
        qcodes, rec, gcur, (const f32x4*)coef, scale, bias, out);
}

// Round 11
// 35.843 us; speedup vs baseline: 3.1267x; 1.8293x over previous
//
#include <hip/hip_runtime.h>
#include <stdint.h>

#define NF    64
#define DIM0  50000
#define SROWS 100000
#define TPB   256
#define QBLKS 3125          // 800000 code-words / 256
#define QGRID 2048          // query blocks (grid-stride, 2 iters max)
#define COEF_OFF_BYTES (SROWS * 32)

typedef float    f32x4 __attribute__((ext_vector_type(4)));
typedef uint32_t u32x4 __attribute__((ext_vector_type(4)));
typedef __fp16   h16x2 __attribute__((ext_vector_type(2)));

#if __has_builtin(__builtin_amdgcn_fdot2)
#define FDOT2(a, b, c) __builtin_amdgcn_fdot2((a), (b), (c), false)
#else
static __device__ inline float FDOT2(h16x2 a, h16x2 b, float c) {
    return fmaf((float)a.x, (float)b.x, fmaf((float)a.y, (float)b.y, c));
}
#endif

// coef buffer layout (u32 words):
//   [0..32)  cw2 : f16x2 pairs (W'[f]*4096, W'[f+4]*4096), f=(t>>2)*8+(t&3)
//   [32..64) cx2 : same for X'
//   [64..96) cy2 : same for Y'
//   [96] Ca (f32), [97] Cb (f32)
// W=V0-V1-V2+V3, X=V1-V3, Y=V2-V3; W'=W/256, X'=W/512+X/16, Y'=W/512+Y/16,
// C=W/1024+(X+Y)/32+V3.

// ---------------------------------------------------------------------------
// Pass 1: closed-form quantize (row = 32B, 64 x 4-bit codes) + coef table.
//   q = clamp(ceil(16*f - 1), 0, 15)  (bit-exact vs jnp.argmin, tie->lower;
//   validated r2-r10, absmax <= 2.4e-7)
// ---------------------------------------------------------------------------
__global__ __launch_bounds__(TPB) void quantize_kernel(
        const float* __restrict__ feats, const float* __restrict__ values,
        uint32_t* __restrict__ qcodes, uint32_t* __restrict__ coef) {
    int t = threadIdx.x;
    if (blockIdx.x == 0 && t < NF) {
        // per-feature linear coefficients (f32)
        float v0 = values[t], v1 = values[NF + t];
        float v2 = values[2 * NF + t], v3 = values[3 * NF + t];
        float W = v0 - v1 - v2 + v3;
        float X = v1 - v3, Y = v2 - v3;
        float C = W * (1.0f / 1024.0f) + (X + Y) * (1.0f / 32.0f) + v3;
        // Ca/Cb: reduce C over each 32-lane half of wave 0
        float Cs = C;
        Cs += __shfl_xor(Cs, 1);  Cs += __shfl_xor(Cs, 2);
        Cs += __shfl_xor(Cs, 4);  Cs += __shfl_xor(Cs, 8);
        Cs += __shfl_xor(Cs, 16);
        if (t == 0)  ((float*)coef)[96] = Cs;
        if (t == 32) ((float*)coef)[97] = Cs;

        // f16 coefficient pairs, scaled by 4096 (keeps f16 well-normal)
        if (t < 32) {
            int flo = (t >> 2) * 8 + (t & 3);      // nibble j pairs with j+4
            int fhi = flo + 4;
#pragma unroll
            for (int which = 0; which < 3; ++which) {
                float clo, chi;
#pragma unroll
                for (int pick = 0; pick < 2; ++pick) {
                    int f = pick ? fhi : flo;
                    float w0 = values[f], w1 = values[NF + f];
                    float w2v = values[2 * NF + f], w3 = values[3 * NF + f];
                    float Wf = w0 - w1 - w2v + w3;
                    float Xf = w1 - w3, Yf = w2v - w3;
                    float c;
                    if (which == 0)      c = Wf * (4096.0f / 256.0f);
                    else if (which == 1) c = (Wf * (1.0f/512.0f) + Xf * (1.0f/16.0f)) * 4096.0f;
                    else                 c = (Wf * (1.0f/512.0f) + Yf * (1.0f/16.0f)) * 4096.0f;
                    if (pick) chi = c; else clo = c;
                }
                h16x2 p = {(__fp16)clo, (__fp16)chi};
                coef[which * 32 + t] = __builtin_bit_cast(uint32_t, p);
            }
        }
    }

    int gid = blockIdx.x * TPB + t;              // word idx = s*8+w (exact)
    const f32x4* fr = (const f32x4*)(feats + (size_t)gid * 8);
    f32x4 fA = __builtin_nontemporal_load(fr);
    f32x4 fB = __builtin_nontemporal_load(fr + 1);
    float fv[8] = {fA.x, fA.y, fA.z, fA.w, fB.x, fB.y, fB.z, fB.w};

    uint32_t word = 0u;
#pragma unroll
    for (int j = 0; j < 8; ++j) {
        float x = fmaf(fv[j], 16.0f, -1.0f);     // exact: 16f-1 representable
        int q = (int)ceilf(x);
        q = q < 0 ? 0 : (q > 15 ? 15 : q);
        word |= (uint32_t)q << (4 * j);
    }
    qcodes[gid] = word;
}

// ---------------------------------------------------------------------------
// Pass 2: 1 query/thread, grid-stride (2 iters). 2 gathered 32B rows/query.
// f16 magic decode: ((w>>4j)&0x000F000F)|0x64006400 bitcast->f16x2 = 1024+n;
// subtract 1024 -> exact (A,B). Products <=225 exact in f16; accumulate f32
// via v_dot2_f32_f16 against x4096-scaled f16 coef pairs; /4096 at the end.
//   asum = (cc_a+ca_a+cb_a)/4096 + Ca ; bsum likewise
//   out  = asum * tanh(bsum) * exp(scale) + bias
// ---------------------------------------------------------------------------
__global__ __launch_bounds__(TPB) void query_kernel(
        const uint32_t* __restrict__ qcodes,
        const uint32_t* __restrict__ coef,
        const float* __restrict__ scale,
        const float* __restrict__ bias,
        const int* __restrict__ idx0,
        const int* __restrict__ idx1,
        float* __restrict__ out, int N) {
    int t = threadIdx.x;
    float es = expf(scale[0]);
    float bi = bias[0];
    float Ca = ((const float*)coef)[96];
    float Cb = ((const float*)coef)[97];

    for (int n = blockIdx.x * TPB + t; n < N; n += QGRID * TPB) {
        int r0 = __builtin_nontemporal_load(idx0 + n);
        int r1 = DIM0 + __builtin_nontemporal_load(idx1 + n);

        const u32x4* pa = (const u32x4*)(qcodes + (size_t)r0 * 8);
        const u32x4* pb = (const u32x4*)(qcodes + (size_t)r1 * 8);
        u32x4 x0 = pa[0], x1 = pa[1];
        u32x4 y0 = pb[0], y1 = pb[1];
        uint32_t aw[8] = {x0.x, x0.y, x0.z, x0.w, x1.x, x1.y, x1.z, x1.w};
        uint32_t bw[8] = {y0.x, y0.y, y0.z, y0.w, y1.x, y1.y, y1.z, y1.w};

        float cc_a = 0.f, ca_a = 0.f, cb_a = 0.f;   // half a (f<32)
        float cc_b = 0.f, ca_b = 0.f, cb_b = 0.f;   // half b (f>=32)
        const h16x2 k1024 = {(__fp16)1024.0f, (__fp16)1024.0f};
#pragma unroll
        for (int wd = 0; wd < 8; ++wd) {
            uint32_t wa = aw[wd];
            uint32_t wb = bw[wd];
#pragma unroll
            for (int j = 0; j < 4; ++j) {
                uint32_t ua = ((wa >> (4 * j)) & 0x000F000Fu) | 0x64006400u;
                uint32_t ub = ((wb >> (4 * j)) & 0x000F000Fu) | 0x64006400u;
                h16x2 a2 = __builtin_bit_cast(h16x2, ua) - k1024;
                h16x2 b2 = __builtin_bit_cast(h16x2, ub) - k1024;
                h16x2 ab = a2 * b2;                  // exact (<=225)
                h16x2 w2 = __builtin_bit_cast(h16x2, coef[wd * 4 + j]);
                h16x2 x2 = __builtin_bit_cast(h16x2, coef[32 + wd * 4 + j]);
                h16x2 y2 = __builtin_bit_cast(h16x2, coef[64 + wd * 4 + j]);
                if (wd < 4) {
                    cc_a = FDOT2(w2, ab, cc_a);
                    ca_a = FDOT2(x2, a2, ca_a);
                    cb_a = FDOT2(y2, b2, cb_a);
                } else {
                    cc_b = FDOT2(w2, ab, cc_b);
                    ca_b = FDOT2(x2, a2, ca_b);
                    cb_b = FDOT2(y2, b2, cb_b);
                }
            }
        }

        float asum = (cc_a + ca_a + cb_a) * (1.0f / 4096.0f) + Ca;
        float bsum = (cc_b + ca_b + cb_b) * (1.0f / 4096.0f) + Cb;
        __builtin_nontemporal_store(asum * tanhf(bsum) * es + bi, out + n);
    }
}

extern "C" void kernel_launch(void* const* d_in, const int* in_sizes, int n_in,
                              void* d_out, int out_size, void* d_ws, size_t ws_size,
                              hipStream_t stream) {
    const float* values = (const float*)d_in[0];  // [1,4,64]
    const float* feats  = (const float*)d_in[1];  // [100000,64]
    const float* scale  = (const float*)d_in[3];  // [1]
    const float* bias   = (const float*)d_in[4];  // [1]
    const int*   idx0   = (const int*)d_in[5];    // [N]
    const int*   idx1   = (const int*)d_in[6];    // [N]
    float*       out    = (float*)d_out;          // [N] f32

    uint32_t* qcodes = (uint32_t*)d_ws;                            // 3.2 MB
    uint32_t* coef   = (uint32_t*)((char*)d_ws + COEF_OFF_BYTES);  // 98 u32

    quantize_kernel<<<QBLKS, TPB, 0, stream>>>(feats, values, qcodes, coef);

    int N = out_size;
    query_kernel<<<QGRID, TPB, 0, stream>>>(
        qcodes, coef, scale, bias, idx0, idx1, out, N);
}